// Round 4
// baseline (242.335 us; speedup 1.0000x reference)
//
#include <hip/hip_runtime.h>

#define Bv   2
#define Nv   8192
#define Cv   128
#define KSv  120
#define KNNv 30

// ---------------------------------------------------------------------------
// Compile-time replication of np.random.RandomState(1234).shuffle(arange(8192))
// -> first 120 entries. MT19937 + Fisher-Yates with rk_interval masked
// rejection (max < 2^32 path).
// ---------------------------------------------------------------------------
namespace mtns {
struct MTState { unsigned mt[624]; int mti; };
constexpr void mt_seed(MTState& s, unsigned seed) {
  for (int pos = 0; pos < 624; ++pos) {
    s.mt[pos] = seed;
    seed = 1812433253u * (seed ^ (seed >> 30)) + (unsigned)pos + 1u;
  }
  s.mti = 624;
}
constexpr unsigned mt_next(MTState& s) {
  if (s.mti >= 624) {
    for (int i = 0; i < 624; ++i) {
      unsigned y = (s.mt[i] & 0x80000000u) | (s.mt[(i + 1) % 624] & 0x7fffffffu);
      unsigned v = s.mt[(i + 397) % 624] ^ (y >> 1);
      s.mt[i] = (y & 1u) ? (v ^ 0x9908b0dfu) : v;
    }
    s.mti = 0;
  }
  unsigned y = s.mt[s.mti++];
  y ^= y >> 11;
  y ^= (y << 7) & 0x9d2c5680u;
  y ^= (y << 15) & 0xefc60000u;
  y ^= y >> 18;
  return y;
}
struct IdxTable { int v[KSv]; };
constexpr IdxTable make_idx() {
  MTState st{};
  mt_seed(st, 1234u);
  int arr[Nv] = {};
  for (int i = 0; i < Nv; ++i) arr[i] = i;
  for (int i = Nv - 1; i > 0; --i) {
    unsigned mask = (unsigned)i;
    mask |= mask >> 1; mask |= mask >> 2; mask |= mask >> 4;
    mask |= mask >> 8; mask |= mask >> 16;
    unsigned j = 0;
    do { j = mt_next(st) & mask; } while (j > (unsigned)i);
    int tmp = arr[i]; arr[i] = arr[(int)j]; arr[(int)j] = tmp;
  }
  IdxTable out{};
  for (int k = 0; k < KSv; ++k) out.v[k] = arr[k];
  return out;
}
}  // namespace mtns

__constant__ mtns::IdxTable IDX = mtns::make_idx();

__device__ __forceinline__ float wave_sum(float v) {
  #pragma unroll
  for (int m = 32; m; m >>= 1) v += __shfl_xor(v, m);
  return v;
}

// Opaque barrier: keeps x*x and the add as SEPARATE f32 roundings (numpy does
// mult-then-add, no FMA, in pairwise_sum) despite -ffp-contract=fast.
__device__ __forceinline__ float opaque(float x) {
  asm volatile("" : "+v"(x));
  return x;
}

// ---------------------------------------------------------------------------
// k0: per sampled row (b, kp):
//   nrm32 = numpy-pairwise f32 norm of inst_s row (8-acc + tree + sqrtf)
//   gn32[c] = inst_s[c] / nrm32   (IEEE f32 division — matches np fn/gn bits)
//   G[b,kp,o] = feat_s . conv_w[o,:128] + key_pt . conv_w[o,128:131]
// grid = 240 blocks (b*120+kp), 128 threads
// ---------------------------------------------------------------------------
__global__ void k0_prepare(const float* __restrict__ points,
                           const float* __restrict__ feature,
                           const float* __restrict__ inst,
                           const float* __restrict__ conv_w,
                           float* __restrict__ gn32W,
                           float* __restrict__ GW) {
  int bk = blockIdx.x;
  int b = bk / KSv, kp = bk % KSv;
  int jg = IDX.v[kp];
  int t = threadIdx.x;
  __shared__ float featS[Cv];
  __shared__ float rowS[Cv];
  __shared__ float ptS[3];
  __shared__ float nAcc[8];
  __shared__ float nrmSh;
  long rowi = (long)b * Nv + jg;
  float iv = inst[rowi * Cv + t];
  rowS[t] = iv;
  featS[t] = feature[rowi * Cv + t];
  if (t < 3) ptS[t] = points[rowi * 3 + t];
  __syncthreads();
  // numpy pairwise_sum(x*x), n=128: r[j] = sum_i x[8i+j]^2 sequential
  if (t < 8) {
    float x0 = rowS[t];
    float acc = opaque(x0 * x0);
    #pragma unroll
    for (int i = 1; i < 16; ++i) {
      float xv = rowS[8 * i + t];
      acc = acc + opaque(xv * xv);
    }
    nAcc[t] = acc;
  }
  __syncthreads();
  if (t == 0) {
    float res = ((nAcc[0] + nAcc[1]) + (nAcc[2] + nAcc[3])) +
                ((nAcc[4] + nAcc[5]) + (nAcc[6] + nAcc[7]));
    nrmSh = sqrtf(res);
  }
  __syncthreads();
  gn32W[(b * KSv + kp) * Cv + t] = iv / nrmSh;   // IEEE f32 div
  const float* cw = conv_w + t * 131;
  float acc = 0.f;
  #pragma unroll 8
  for (int c = 0; c < Cv; ++c) acc = fmaf(featS[c], cw[c], acc);
  acc = fmaf(ptS[0], cw[128], fmaf(ptS[1], cw[129], fmaf(ptS[2], cw[130], acc)));
  GW[(b * KSv + kp) * Cv + t] = acc;
}

// ---------------------------------------------------------------------------
// k2: main per-row kernel. 512 blocks x 256 threads; 2 rows in flight
// (r = tid>>7, t = tid&127).
// dist mimics numpy f32: fn = row/nrm32 (pairwise norm, f32 div), dot via
// single 16-lane FMA accumulator in ascending c order (npyv AVX512 mimic),
// _mm512_reduce_add_ps halving tree, then "- 1.0f" BEFORE ranking. Rank is
// stable (index tiebreak) = lax.top_k. Then 30->30->30 MLP + softmax, and
// attn*(G - PW) scan -> per-channel max/min + group sum/sumsq partials
// (GN affine + leaky + max_k commute; gamma sign picks max vs min).
// ---------------------------------------------------------------------------
__global__ __launch_bounds__(256) void k2_main(
    const float* __restrict__ points,
    const float* __restrict__ inst,
    const float* __restrict__ w1,
    const float* __restrict__ w2,
    const float* __restrict__ conv_w,
    const float* __restrict__ gn32,
    const float* __restrict__ GW,
    float* __restrict__ Mmax, float* __restrict__ Mmin,
    float2* __restrict__ part) {
  __shared__ float4 gnS[KSv * 32];        // 61440 B, swizzled
  __shared__ float4 instS4[2][32];        // raw row, then overwritten with fn
  __shared__ float4 distS4[2][32];        // f32 dists (120 used)
  __shared__ float tvS[2][KNNv];
  __shared__ int   tiS[2][KNNv];
  __shared__ float attnS[2][KNNv];
  __shared__ float aS[2][KNNv];
  __shared__ float ptS[2][3];
  __shared__ float nAccS[2][8];
  __shared__ float nrmS[2];
  __shared__ float sredS[2];

  int bid = blockIdx.x;
  int b = bid >> 8;            // 256 blocks per batch
  int chunk = bid & 255;
  int tid = threadIdx.x;
  int r = tid >> 7;
  int t = tid & 127;

  // stage gn32 (swizzled so the per-row float4 walk is bank-balanced)
  const float4* gnG = (const float4*)(gn32 + (long)b * KSv * Cv);
  for (int i = tid; i < KSv * 32; i += 256) {
    int kp = i >> 5, c4 = i & 31;
    gnS[kp * 32 + (c4 ^ (kp & 31))] = gnG[i];
  }
  // per-thread invariants (channel o = t)
  float c128 = conv_w[t * 131 + 128];
  float c129 = conv_w[t * 131 + 129];
  float c130 = conv_w[t * 131 + 130];
  const float* Gb = GW + (long)b * KSv * Cv;
  __syncthreads();

  for (int it = 0; it < 16; ++it) {
    int n = chunk * 32 + it * 2 + r;
    long row = (long)b * Nv + n;
    float iv = inst[row * Cv + t];
    ((float*)instS4[r])[t] = iv;
    if (t < 3) ptS[r][t] = points[row * 3 + t];
    __syncthreads();
    // numpy pairwise norm of the query row
    if (t < 8) {
      const float* xr = (const float*)instS4[r];
      float x0 = xr[t];
      float acc = opaque(x0 * x0);
      #pragma unroll
      for (int i = 1; i < 16; ++i) {
        float xv = xr[8 * i + t];
        acc = acc + opaque(xv * xv);
      }
      nAccS[r][t] = acc;
    }
    __syncthreads();
    if (t == 0) {
      const float* rr = nAccS[r];
      float res = ((rr[0] + rr[1]) + (rr[2] + rr[3])) +
                  ((rr[4] + rr[5]) + (rr[6] + rr[7]));
      nrmS[r] = sqrtf(res);
    }
    __syncthreads();
    float fnv = iv / nrmS[r];              // IEEE f32 div (matches np fn)
    ((float*)instS4[r])[t] = fnv;
    __syncthreads();

    // dist[t] for t<120: npyv-mimic f32 dot: 16 lane-accumulators (c mod 16)
    // FMA in ascending c, then AVX512 reduce tree; subtract 1.0f AFTER.
    float d = 0.f;
    if (t < KSv) {
      const float4* irow = instS4[r];
      const float4* grow = gnS + t * 32;
      int sw = t & 31;
      float4 a0 = {0,0,0,0}, a1 = {0,0,0,0}, a2 = {0,0,0,0}, a3 = {0,0,0,0};
      #pragma unroll
      for (int c4 = 0; c4 < 32; c4 += 4) {
        float4 g0 = grow[(c4 + 0) ^ sw]; float4 f0 = irow[c4 + 0];
        float4 g1 = grow[(c4 + 1) ^ sw]; float4 f1 = irow[c4 + 1];
        float4 g2 = grow[(c4 + 2) ^ sw]; float4 f2 = irow[c4 + 2];
        float4 g3 = grow[(c4 + 3) ^ sw]; float4 f3 = irow[c4 + 3];
        a0.x = fmaf(g0.x, f0.x, a0.x); a0.y = fmaf(g0.y, f0.y, a0.y);
        a0.z = fmaf(g0.z, f0.z, a0.z); a0.w = fmaf(g0.w, f0.w, a0.w);
        a1.x = fmaf(g1.x, f1.x, a1.x); a1.y = fmaf(g1.y, f1.y, a1.y);
        a1.z = fmaf(g1.z, f1.z, a1.z); a1.w = fmaf(g1.w, f1.w, a1.w);
        a2.x = fmaf(g2.x, f2.x, a2.x); a2.y = fmaf(g2.y, f2.y, a2.y);
        a2.z = fmaf(g2.z, f2.z, a2.z); a2.w = fmaf(g2.w, f2.w, a2.w);
        a3.x = fmaf(g3.x, f3.x, a3.x); a3.y = fmaf(g3.y, f3.y, a3.y);
        a3.z = fmaf(g3.z, f3.z, a3.z); a3.w = fmaf(g3.w, f3.w, a3.w);
      }
      // _mm512_reduce_add_ps tree over lanes L = 4m+k:
      float4 h0, h1, h; 
      h0.x = a0.x + a2.x; h0.y = a0.y + a2.y; h0.z = a0.z + a2.z; h0.w = a0.w + a2.w;
      h1.x = a1.x + a3.x; h1.y = a1.y + a3.y; h1.z = a1.z + a3.z; h1.w = a1.w + a3.w;
      h.x = h0.x + h1.x; h.y = h0.y + h1.y; h.z = h0.z + h1.z; h.w = h0.w + h1.w;
      float sx = h.x + h.z;
      float sy = h.y + h.w;
      float dot = sx + sy;
      d = dot - 1.0f;                      // f32 shift BEFORE ranking
    }
    __syncthreads();
    if (t < KSv) ((float*)distS4[r])[t] = d;
    __syncthreads();

    // stable rank: rank = #{j: d_j > d_t or (d_j==d_t and j<t)}; rank<30 wins
    if (t < KSv) {
      int rank = 0;
      const float4* dv = distS4[r];
      #pragma unroll
      for (int j4 = 0; j4 < KSv / 4; ++j4) {
        float4 w = dv[j4];
        int base = j4 * 4;
        rank += (w.x > d) || (w.x == d && (base + 0) < t);
        rank += (w.y > d) || (w.y == d && (base + 1) < t);
        rank += (w.z > d) || (w.z == d && (base + 2) < t);
        rank += (w.w > d) || (w.w == d && (base + 3) < t);
      }
      if (rank < KNNv) { tvS[r][rank] = d; tiS[r][rank] = t; }
    }
    __syncthreads();

    // a = relu(W1 . topk_dist)
    if (t < KNNv) {
      float a = 0.f;
      #pragma unroll
      for (int k = 0; k < KNNv; ++k) a = fmaf(tvS[r][k], w1[t * KNNv + k], a);
      aS[r][t] = fmaxf(a, 0.f);
    }
    __syncthreads();
    // a2 = W2 . a
    if (t < KNNv) {
      float a2 = 0.f;
      #pragma unroll
      for (int o = 0; o < KNNv; ++o) a2 = fmaf(aS[r][o], w2[t * KNNv + o], a2);
      attnS[r][t] = a2;
    }
    __syncthreads();
    // softmax over 30
    if (t == 0) {
      float mx = attnS[r][0];
      for (int k = 1; k < KNNv; ++k) mx = fmaxf(mx, attnS[r][k]);
      sredS[r] = mx;
    }
    __syncthreads();
    if (t < KNNv) attnS[r][t] = __expf(attnS[r][t] - sredS[r]);
    __syncthreads();
    if (t == 0) {
      float s = 0.f;
      for (int k = 0; k < KNNv; ++k) s += attnS[r][k];
      sredS[r] = 1.0f / s;
    }
    __syncthreads();
    if (t < KNNv) attnS[r][t] *= sredS[r];
    __syncthreads();

    // y scan: y_k = attn_k * (G[j_k][t] - PW_t); track max/min/sum/sumsq
    float pw = fmaf(ptS[r][0], c128, fmaf(ptS[r][1], c129, ptS[r][2] * c130));
    float mx = -__builtin_inff(), mn = __builtin_inff(), s = 0.f, q = 0.f;
    #pragma unroll
    for (int k = 0; k < KNNv; ++k) {
      float ak = attnS[r][k];
      int jk = tiS[r][k];
      float g = Gb[jk * Cv + t];
      float yv = ak * (g - pw);
      mx = fmaxf(mx, yv);
      mn = fminf(mn, yv);
      s += yv;
      q = fmaf(yv, yv, q);
    }
    Mmax[row * Cv + t] = mx;
    Mmin[row * Cv + t] = mn;
    float s2 = wave_sum(s), q2 = wave_sum(q);
    if ((t & 63) == 0) part[row * 2 + (t >> 6)] = make_float2(s2, q2);
    __syncthreads();
  }
}

// ---------------------------------------------------------------------------
// k3: reduce per-row group partials -> (mu, rsqrt(var+eps)) per (b, group)
// ---------------------------------------------------------------------------
__global__ void k3_stats(const float2* __restrict__ part,
                         float2* __restrict__ stats) {
  int bg = blockIdx.x;                   // b*2+g
  int b = bg >> 1, g = bg & 1;
  int tid = threadIdx.x;
  __shared__ double sd[256], qd[256];
  double s = 0, q = 0;
  for (int i = tid; i < Nv; i += 256) {
    float2 p = part[((long)b * Nv + i) * 2 + g];
    s += p.x;
    q += p.y;
  }
  sd[tid] = s; qd[tid] = q;
  __syncthreads();
  for (int st = 128; st > 0; st >>= 1) {
    if (tid < st) { sd[tid] += sd[tid + st]; qd[tid] += qd[tid + st]; }
    __syncthreads();
  }
  if (tid == 0) {
    const double cnt = 64.0 * 30.0 * 8192.0;
    double mu = sd[0] / cnt;
    double var = qd[0] / cnt - mu * mu;
    double rs = 1.0 / sqrt(var + 1e-5);
    stats[bg] = make_float2((float)mu, (float)rs);
  }
}

// ---------------------------------------------------------------------------
// k4: GN affine + leaky on max-pooled channel (monotone => pick Mmax/Mmin by
// sign of gamma), then 3x256 output MLP. One block (128 thr) per row.
// ---------------------------------------------------------------------------
__global__ void k4_out(const float* __restrict__ feature,
                       const float* __restrict__ gamma,
                       const float* __restrict__ beta,
                       const float* __restrict__ mlp_w,
                       const float* __restrict__ mlp_b,
                       const float* __restrict__ Mmax,
                       const float* __restrict__ Mmin,
                       const float2* __restrict__ stats,
                       float* __restrict__ out) {
  long row = blockIdx.x;
  int b = (int)(row >> 13), n = (int)(row & (Nv - 1));
  int t = threadIdx.x;                   // channel
  int g = t >> 6;
  float2 st = stats[b * 2 + g];
  float gam = gamma[t], bet = beta[t];
  float M = (gam >= 0.f) ? Mmax[row * Cv + t] : Mmin[row * Cv + t];
  float yv = fmaf((M - st.x) * st.y, gam, bet);
  yv = (yv >= 0.f) ? yv : 0.2f * yv;
  float fv = feature[row * Cv + t];
  float o0 = yv * mlp_w[0 * 256 + t] + fv * mlp_w[0 * 256 + 128 + t];
  float o1 = yv * mlp_w[1 * 256 + t] + fv * mlp_w[1 * 256 + 128 + t];
  float o2 = yv * mlp_w[2 * 256 + t] + fv * mlp_w[2 * 256 + 128 + t];
  o0 = wave_sum(o0);
  o1 = wave_sum(o1);
  o2 = wave_sum(o2);
  __shared__ float red[2][3];
  if ((t & 63) == 0) { red[t >> 6][0] = o0; red[t >> 6][1] = o1; red[t >> 6][2] = o2; }
  __syncthreads();
  if (t < 3)
    out[(long)b * 3 * Nv + (long)t * Nv + n] = red[0][t] + red[1][t] + mlp_b[t];
}

extern "C" void kernel_launch(void* const* d_in, const int* in_sizes, int n_in,
                              void* d_out, int out_size, void* d_ws, size_t ws_size,
                              hipStream_t stream) {
  const float* points  = (const float*)d_in[0];
  const float* feature = (const float*)d_in[1];
  const float* inst    = (const float*)d_in[2];
  const float* w1      = (const float*)d_in[3];
  const float* w2      = (const float*)d_in[4];
  const float* conv_w  = (const float*)d_in[5];
  const float* gamma   = (const float*)d_in[6];
  const float* beta    = (const float*)d_in[7];
  const float* mlp_w   = (const float*)d_in[8];
  const float* mlp_b   = (const float*)d_in[9];
  float* out = (float*)d_out;

  // workspace layout (bytes):
  //   gn32  [0,       122880)   2*120*128 f32
  //   GW    [122880,  245760)   2*120*128 f32
  //   Mmax  [245760,  +8MB)     2*8192*128 f32
  //   Mmin  [.. +8MB)
  //   part  [.., +256KB)        2*8192*2 float2
  //   stats [.., +32)           4 float2
  char* ws = (char*)d_ws;
  float* gn32  = (float*)(ws);
  float* GW    = (float*)(ws + 122880);
  float* Mmax  = (float*)(ws + 245760);
  float* Mmin  = (float*)(ws + 245760 + 8388608);
  float2* part = (float2*)(ws + 245760 + 2 * 8388608);
  float2* stats= (float2*)(ws + 245760 + 2 * 8388608 + 262144);

  k0_prepare<<<dim3(Bv * KSv), dim3(128), 0, stream>>>(points, feature, inst,
                                                       conv_w, gn32, GW);
  k2_main<<<dim3(512), dim3(256), 0, stream>>>(points, inst, w1, w2, conv_w,
                                               gn32, GW, Mmax, Mmin, part);
  k3_stats<<<dim3(4), dim3(256), 0, stream>>>(part, stats);
  k4_out<<<dim3(Bv * Nv), dim3(128), 0, stream>>>(feature, gamma, beta, mlp_w,
                                                  mlp_b, Mmax, Mmin, stats, out);
}